// Round 3
// baseline (1506.681 us; speedup 1.0000x reference)
//
#include <hip/hip_runtime.h>
#include <hip/hip_bf16.h>
#include <math.h>

// Problem constants
// B=64, H=W=56, C=192, NH=6, WS=7, SS=3, N=49, HD=32, MLP_H=768
// M (rows through all GEMMs) = B*H*W = 200704 = 1568*128
// ALL inputs / output are FP32 (per reference dtypes). Internally: bf16 MFMA.

typedef __attribute__((ext_vector_type(8))) short short8;
typedef __attribute__((ext_vector_type(4))) float floatx4;

static __device__ __forceinline__ float bf2f(__hip_bfloat16 v) { return __bfloat162float(v); }

// ---------------------------------------------------------------------------
// Convert the 4 weight matrices fp32 -> bf16 into ws.
// Layout (elements): qkv_w @0 (110592), proj_w @110592 (36864),
//                    fc1_w @147456 (147456), fc2_w @294912 (147456). Total 442368.
// ---------------------------------------------------------------------------
__global__ __launch_bounds__(256)
void cvt_w(const float* __restrict__ a, const float* __restrict__ b,
           const float* __restrict__ c, const float* __restrict__ d,
           __hip_bfloat16* __restrict__ o)
{
    int i = blockIdx.x * 256 + threadIdx.x;
    float v;
    if (i < 110592)      v = a[i];
    else if (i < 147456) v = b[i - 110592];
    else if (i < 294912) v = c[i - 147456];
    else                 v = d[i - 294912];
    o[i] = __float2bfloat16(v);
}

// ---------------------------------------------------------------------------
// LN1 + cyclic shift (-3,-3) + window partition. One wave per row.
// fp32 in, bf16 out (GEMM A operand).
// ---------------------------------------------------------------------------
__global__ __launch_bounds__(256)
void ln1_shift_win(const float* __restrict__ x,
                   const float* __restrict__ g,
                   const float* __restrict__ bt,
                   __hip_bfloat16* __restrict__ yw)
{
    int r = blockIdx.x * 4 + (threadIdx.x >> 6);
    int lane = threadIdx.x & 63;
    int win = r / 49, t = r - win * 49;
    int b = win >> 6, wi = win & 63;
    int wh = wi >> 3, ww = wi & 7;
    int tr = t / 7, tc = t - tr * 7;
    int hs = wh * 7 + tr + 3; if (hs >= 56) hs -= 56;   // roll(-3): shifted[p] = x[(p+3)%56]
    int ws = ww * 7 + tc + 3; if (ws >= 56) ws -= 56;
    const float* src = x + ((size_t)b * 3136 + hs * 56 + ws) * 192;
    float v0 = src[lane];
    float v1 = src[lane + 64];
    float v2 = src[lane + 128];
    float s  = v0 + v1 + v2;
    float s2 = v0 * v0 + v1 * v1 + v2 * v2;
#pragma unroll
    for (int off = 32; off; off >>= 1) { s += __shfl_xor(s, off); s2 += __shfl_xor(s2, off); }
    float mean = s * (1.0f / 192.0f);
    float var  = s2 * (1.0f / 192.0f) - mean * mean;
    float rstd = rsqrtf(var + 1e-5f);
    __hip_bfloat16* dst = yw + (size_t)r * 192;
    dst[lane]       = __float2bfloat16((v0 - mean) * rstd * g[lane]       + bt[lane]);
    dst[lane + 64]  = __float2bfloat16((v1 - mean) * rstd * g[lane + 64]  + bt[lane + 64]);
    dst[lane + 128] = __float2bfloat16((v2 - mean) * rstd * g[lane + 128] + bt[lane + 128]);
}

// ---------------------------------------------------------------------------
// LN2: fp32 x1 (d_out) -> bf16 z. One wave per row.
// ---------------------------------------------------------------------------
__global__ __launch_bounds__(256)
void ln2_kernel(const float* __restrict__ x1,
                const float* __restrict__ g,
                const float* __restrict__ bt,
                __hip_bfloat16* __restrict__ z)
{
    int r = blockIdx.x * 4 + (threadIdx.x >> 6);
    int lane = threadIdx.x & 63;
    const float* src = x1 + (size_t)r * 192;
    float v0 = src[lane];
    float v1 = src[lane + 64];
    float v2 = src[lane + 128];
    float s  = v0 + v1 + v2;
    float s2 = v0 * v0 + v1 * v1 + v2 * v2;
#pragma unroll
    for (int off = 32; off; off >>= 1) { s += __shfl_xor(s, off); s2 += __shfl_xor(s2, off); }
    float mean = s * (1.0f / 192.0f);
    float var  = s2 * (1.0f / 192.0f) - mean * mean;
    float rstd = rsqrtf(var + 1e-5f);
    __hip_bfloat16* dst = z + (size_t)r * 192;
    dst[lane]       = __float2bfloat16((v0 - mean) * rstd * g[lane]       + bt[lane]);
    dst[lane + 64]  = __float2bfloat16((v1 - mean) * rstd * g[lane + 64]  + bt[lane + 64]);
    dst[lane + 128] = __float2bfloat16((v2 - mean) * rstd * g[lane + 128] + bt[lane + 128]);
}

// ---------------------------------------------------------------------------
// Attention: one block per (head, local window). qkv (bf16) pre-offset per
// chunk; chunk starts are multiples of 64 windows so win&63 is offset-invariant.
// rpb/gate fp32. o written bf16 (proj GEMM A operand).
// ---------------------------------------------------------------------------
__device__ __forceinline__ int regio(int r) { return r < 49 ? 0 : (r < 53 ? 1 : 2); }

__global__ __launch_bounds__(256)
void attn_kernel(const __hip_bfloat16* __restrict__ qkv,
                 const float* __restrict__ rpb,
                 const float* __restrict__ gate,
                 __hip_bfloat16* __restrict__ o)
{
    const int head = blockIdx.x;       // 0..5
    const int win  = blockIdx.y;       // local window in chunk
    const int wi   = win & 63;
    const int wh = wi >> 3, ww = wi & 7;
    const int tid = threadIdx.x;

    __shared__ float q[49 * 32];
    __shared__ float k[49 * 32];
    __shared__ float v[49 * 32];
    __shared__ float p[49 * 49];

    const __hip_bfloat16* base = qkv + (size_t)win * 49 * 576 + head * 32;
    for (int idx = tid; idx < 1568; idx += 256) {
        int t = idx >> 5, d = idx & 31;
        q[idx] = bf2f(base[t * 576 + d]);
        k[idx] = bf2f(base[t * 576 + 192 + d]);
        v[idx] = bf2f(base[t * 576 + 384 + d]);
    }
    __syncthreads();

    for (int idx = tid; idx < 2401; idx += 256) {
        int i = idx / 49, j = idx - (idx / 49) * 49;
        float s = 0.f;
#pragma unroll
        for (int d = 0; d < 32; ++d) s += q[i * 32 + d] * k[j * 32 + d];
        s *= 0.17677669529663689f;  // 32^-0.5
        int ri = i / 7, ci = i - ri * 7;
        int rj = j / 7, cj = j - rj * 7;
        int bidx = (ri - rj + 6) * 13 + (ci - cj + 6);
        s += rpb[bidx * 6 + head];
        int regi = regio(wh * 7 + ri) * 3 + regio(ww * 7 + ci);
        int regj = regio(wh * 7 + rj) * 3 + regio(ww * 7 + cj);
        if (regi != regj) s -= 100.0f;
        p[idx] = s;
    }
    __syncthreads();

    if (tid < 49) {
        float mx = -1e30f;
        for (int j = 0; j < 49; ++j) mx = fmaxf(mx, p[tid * 49 + j]);
        float sum = 0.f;
        for (int j = 0; j < 49; ++j) { float e = expf(p[tid * 49 + j] - mx); p[tid * 49 + j] = e; sum += e; }
        float gt = 1.0f / (1.0f + expf(-gate[head]));
        float inv = gt / sum;
        for (int j = 0; j < 49; ++j) p[tid * 49 + j] *= inv;
    }
    __syncthreads();

    for (int idx = tid; idx < 1568; idx += 256) {
        int i = idx >> 5, d = idx & 31;
        float s = 0.f;
        for (int m = 0; m < 49; ++m) s += p[i * 49 + m] * v[m * 32 + d];
        o[((size_t)win * 49 + i) * 192 + head * 32 + d] = __float2bfloat16(s);
    }
}

// ---------------------------------------------------------------------------
// MFMA GEMM: C[M,Ncols] = A[M,K] @ W[Ncols,K]^T + bias, tile 128x64,
// 4 waves (2x2), each wave 64x32 via 4x2 mfma_f32_16x16x32_bf16.
// A,W bf16; bias/ex fp32.
// MODE 0: qkv store (bf16 Out). MODE 1: proj + window-reverse scatter +
// residual x (fp32 Out = d_out). MODE 2: fc1 + BN + GELU (bf16 Out).
// MODE 3: fc2 + residual x1 (fp32 Out = d_out chunk).
// ---------------------------------------------------------------------------
template <int MODE>
__global__ __launch_bounds__(256, 2)
void gemm_bt(const __hip_bfloat16* __restrict__ A,
             const __hip_bfloat16* __restrict__ W,
             const float* __restrict__ bias,
             const float* __restrict__ ex0,
             const float* __restrict__ ex1,
             void* __restrict__ OutV,
             int K, int Ncols)
{
    __shared__ __align__(16) char lds[(128 * 32 + 64 * 32) * 2];  // A: 8KB, B: 4KB
    short* sA = (short*)lds;
    short* sB = (short*)(lds + 8192);

    const int tid  = threadIdx.x;
    const int wave = tid >> 6, lane = tid & 63;
    const int m0 = blockIdx.x * 128;
    const int n0 = blockIdx.y * 64;
    const int wm = wave >> 1, wn = wave & 1;
    const int lm = lane & 15, quad = lane >> 4;

    floatx4 acc[4][2];
#pragma unroll
    for (int mt = 0; mt < 4; ++mt)
#pragma unroll
        for (int nt = 0; nt < 2; ++nt) acc[mt][nt] = (floatx4){0.f, 0.f, 0.f, 0.f};

    for (int kk = 0; kk < K; kk += 32) {
        // Stage A tile: 128x32 bf16 = 512 x 16B chunks; chunk c = i*256 + tid
#pragma unroll
        for (int i = 0; i < 2; ++i) {
            int c = i * 256 + tid;
            int row = c >> 2, kc = c & 3;
            const __hip_bfloat16* gp = A + (size_t)(m0 + row) * K + kk + kc * 8;
            char* lp = lds + (i * 256 + wave * 64) * 16;  // wave-uniform base
            __builtin_amdgcn_global_load_lds((const __attribute__((address_space(1))) void*)gp,
                                             (__attribute__((address_space(3))) void*)lp, 16, 0, 0);
        }
        // Stage B tile: 64x32 bf16 = 256 x 16B chunks
        {
            int c = tid;
            int row = c >> 2, kc = c & 3;
            const __hip_bfloat16* gp = W + (size_t)(n0 + row) * K + kk + kc * 8;
            char* lp = lds + 8192 + (wave * 64) * 16;
            __builtin_amdgcn_global_load_lds((const __attribute__((address_space(1))) void*)gp,
                                             (__attribute__((address_space(3))) void*)lp, 16, 0, 0);
        }
        asm volatile("s_waitcnt vmcnt(0)" ::: "memory");
        __syncthreads();

        short8 af[4], bf[2];
#pragma unroll
        for (int mt = 0; mt < 4; ++mt)
            af[mt] = *(const short8*)(sA + ((wm * 64 + mt * 16 + lm) * 32 + quad * 8));
#pragma unroll
        for (int nt = 0; nt < 2; ++nt)
            bf[nt] = *(const short8*)(sB + ((wn * 32 + nt * 16 + lm) * 32 + quad * 8));
#pragma unroll
        for (int mt = 0; mt < 4; ++mt)
#pragma unroll
            for (int nt = 0; nt < 2; ++nt)
                acc[mt][nt] = __builtin_amdgcn_mfma_f32_16x16x32_bf16(af[mt], bf[nt], acc[mt][nt], 0, 0, 0);
        __syncthreads();
    }

    // Epilogue. D mapping: col = lane&15, row = quad*4 + reg.
#pragma unroll
    for (int mt = 0; mt < 4; ++mt) {
#pragma unroll
        for (int nt = 0; nt < 2; ++nt) {
            int col = n0 + wn * 32 + nt * 16 + lm;
            float bcol = bias[col];
#pragma unroll
            for (int rg = 0; rg < 4; ++rg) {
                int row = m0 + wm * 64 + mt * 16 + quad * 4 + rg;
                float val = acc[mt][nt][rg] + bcol;
                if (MODE == 0) {
                    ((__hip_bfloat16*)OutV)[(size_t)row * Ncols + col] = __float2bfloat16(val);
                } else if (MODE == 1) {
                    int win = row / 49, t = row - win * 49;
                    int b = win >> 6, wi = win & 63;
                    int wh = wi >> 3, ww = wi & 7;
                    int tr = t / 7, tc = t - tr * 7;
                    int h = wh * 7 + tr + 3; if (h >= 56) h -= 56;  // reverse roll(+3)
                    int w = ww * 7 + tc + 3; if (w >= 56) w -= 56;
                    size_t dst = ((size_t)b * 3136 + h * 56 + w) * 192 + col;
                    ((float*)OutV)[dst] = val + ex0[dst];          // + shortcut x
                } else if (MODE == 2) {
                    float t2 = val * (ex0[col] * 0.99999500003749968f) + ex1[col];
                    float ge = 0.5f * t2 * (1.0f + erff(t2 * 0.70710678118654752f));
                    ((__hip_bfloat16*)OutV)[(size_t)row * Ncols + col] = __float2bfloat16(ge);
                } else {  // MODE 3
                    size_t dst = (size_t)row * Ncols + col;
                    ((float*)OutV)[dst] = val + ex0[dst];          // + x1 residual
                }
            }
        }
    }
}

// ---------------------------------------------------------------------------
extern "C" void kernel_launch(void* const* d_in, const int* in_sizes, int n_in,
                              void* d_out, int out_size, void* d_ws, size_t ws_size,
                              hipStream_t stream)
{
    const float* x      = (const float*)d_in[0];
    const float* n1g    = (const float*)d_in[1];
    const float* n1b    = (const float*)d_in[2];
    const float* qkv_w  = (const float*)d_in[3];
    const float* qkv_b  = (const float*)d_in[4];
    const float* rpb    = (const float*)d_in[5];
    const float* gate   = (const float*)d_in[6];
    const float* proj_w = (const float*)d_in[7];
    const float* proj_b = (const float*)d_in[8];
    const float* n2g    = (const float*)d_in[9];
    const float* n2b    = (const float*)d_in[10];
    const float* fc1_w  = (const float*)d_in[11];
    const float* fc1_b  = (const float*)d_in[12];
    const float* bn_g   = (const float*)d_in[13];
    const float* bn_b   = (const float*)d_in[14];
    const float* fc2_w  = (const float*)d_in[15];
    const float* fc2_b  = (const float*)d_in[16];
    float* out = (float*)d_out;

    char* ws = (char*)d_ws;
    // buf0 @0: 77,070,336 B (yw -> o -> z; 200704 x 192 bf16)
    // buf1 @77,070,336: per-chunk qkv / h (bf16); max = 77,070,336 (NCH=4) or 38,535,168 (NCH=8)
    // wbuf: bf16 weights, 884,736 B, after buf1.
    const int NCH = (ws_size >= 155025408u) ? 4 : 8;   // ws_size constant across calls
    const size_t buf1max = (NCH == 4) ? 77070336u : 38535168u;
    __hip_bfloat16* buf0 = (__hip_bfloat16*)(ws);
    __hip_bfloat16* buf1 = (__hip_bfloat16*)(ws + 77070336);
    __hip_bfloat16* wbuf = (__hip_bfloat16*)(ws + 77070336 + buf1max);
    __hip_bfloat16* wq = wbuf;            // 110592
    __hip_bfloat16* wp = wbuf + 110592;   // 36864
    __hip_bfloat16* w1 = wbuf + 147456;   // 147456
    __hip_bfloat16* w2 = wbuf + 294912;   // 147456

    const int WINS = 4096 / NCH;        // windows per chunk (multiple of 64)
    const int ROWS = WINS * 49;         // rows per chunk
    const int GX   = ROWS / 128;        // gemm grid.x per chunk

    // 0. Weights fp32 -> bf16
    cvt_w<<<dim3(1728), 256, 0, stream>>>(qkv_w, proj_w, fc1_w, fc2_w, wbuf);

    // 1. LN1 + shift + window partition (all rows)
    ln1_shift_win<<<dim3(200704 / 4), 256, 0, stream>>>(x, n1g, n1b, buf0);

    // 2+3. Per chunk: QKV gemm then attention (o overwrites consumed yw rows)
    for (int c = 0; c < NCH; ++c) {
        const __hip_bfloat16* ywc = buf0 + (size_t)c * ROWS * 192;
        __hip_bfloat16*       oc  = buf0 + (size_t)c * ROWS * 192;
        gemm_bt<0><<<dim3(GX, 9), 256, 0, stream>>>(ywc, wq, qkv_b, nullptr, nullptr, buf1, 192, 576);
        attn_kernel<<<dim3(6, WINS), 256, 0, stream>>>(buf1, rpb, gate, oc);
    }

    // 4. proj gemm + window reverse + unshift + shortcut -> x1 (fp32) in d_out
    gemm_bt<1><<<dim3(1568, 3), 256, 0, stream>>>(buf0, wp, proj_b, x, nullptr, out, 192, 192);

    // 5. LN2 (all rows); z (bf16) overwrites o in buf0
    ln2_kernel<<<dim3(200704 / 4), 256, 0, stream>>>(out, n2g, n2b, buf0);

    // 6+7. Per chunk: FC1+BN+GELU -> h (buf1, bf16), FC2 + residual -> out (fp32)
    for (int c = 0; c < NCH; ++c) {
        const __hip_bfloat16* zc = buf0 + (size_t)c * ROWS * 192;
        float*                xc = out  + (size_t)c * ROWS * 192;
        gemm_bt<2><<<dim3(GX, 12), 256, 0, stream>>>(zc, w1, fc1_b, bn_g, bn_b, buf1, 192, 768);
        gemm_bt<3><<<dim3(GX, 3), 256, 0, stream>>>(buf1, w2, fc2_b, xc, nullptr, xc, 768, 192);
    }
}